// Round 1
// baseline (1092.889 us; speedup 1.0000x reference)
//
#include <hip/hip_runtime.h>

#define DIM    2048
#define SEQ    2048
#define BATCH  4
#define NH     16
#define NKV    4
#define HD     128
#define QKVN   3072
#define ROWS   (BATCH*SEQ)   // 8192

typedef __bf16 bf16;
typedef __bf16 bf16x2 __attribute__((ext_vector_type(2)));
typedef __bf16 bf16x4 __attribute__((ext_vector_type(4)));
typedef __bf16 bf16x8 __attribute__((ext_vector_type(8)));
typedef float  f32x4  __attribute__((ext_vector_type(4)));

__device__ __forceinline__ void gload_lds16(const void* g, void* l) {
  __builtin_amdgcn_global_load_lds(
      (const __attribute__((address_space(1))) void*)g,
      (__attribute__((address_space(3))) void*)l, 16, 0, 0);
}

// ---------------- small prep kernels ----------------

__global__ void convert_f32_bf16(const float* __restrict__ in, bf16* __restrict__ out, int n) {
  int i = (blockIdx.x * 256 + threadIdx.x) * 4;
  if (i < n) {
    float4 v = *(const float4*)(in + i);
    bf16x4 t = {(bf16)v.x, (bf16)v.y, (bf16)v.z, (bf16)v.w};
    *(bf16x4*)(out + i) = t;
  }
}

// in [R][C] fp32 -> out [C][R] bf16
__global__ void transpose_w(const float* __restrict__ in, bf16* __restrict__ out, int R, int C) {
  __shared__ float t[64][65];
  int c0 = blockIdx.x * 64, r0 = blockIdx.y * 64;
  int tx = threadIdx.x & 63, ty = threadIdx.x >> 6;
  for (int i = ty; i < 64; i += 4) t[i][tx] = in[(size_t)(r0 + i) * C + c0 + tx];
  __syncthreads();
  for (int i = ty; i < 64; i += 4) out[(size_t)(c0 + i) * R + r0 + tx] = (bf16)t[tx][i];
}

// v [z][2048][128] bf16 -> vT [z][128][2048] bf16
__global__ void transpose_v(const bf16* __restrict__ vb, bf16* __restrict__ vT) {
  __shared__ bf16 t[64][65];
  int z = blockIdx.z;
  const bf16* in = vb + (size_t)z * SEQ * HD;
  bf16* out = vT + (size_t)z * HD * SEQ;
  int d0 = blockIdx.x * 64, s0 = blockIdx.y * 64;
  int tx = threadIdx.x & 63, ty = threadIdx.x >> 6;
  for (int i = ty; i < 64; i += 4) t[i][tx] = in[(size_t)(s0 + i) * HD + d0 + tx];
  __syncthreads();
  for (int i = ty; i < 64; i += 4) out[(size_t)(d0 + i) * SEQ + s0 + tx] = t[tx][i];
}

__global__ void rope_tables(float* __restrict__ cosT, float* __restrict__ sinT) {
  int idx = blockIdx.x * 256 + threadIdx.x;  // SEQ*64
  int s = idx >> 6, j = idx & 63;
  float inv = powf(10000.0f, -(float)j * (1.0f / 64.0f));
  float ang = (float)s * inv;
  cosT[idx] = cosf(ang);
  sinT[idx] = sinf(ang);
}

// ---------------- m97-style bf16 MFMA GEMM, B transposed ----------------
// C[M][N] = A[M][K] * BT[N][K]^T ; tiles 128x128, BK=32, 256 threads
template <typename OutT>
__global__ __launch_bounds__(256, 2) void gemm_bt(
    const bf16* __restrict__ A, const bf16* __restrict__ BT,
    OutT* __restrict__ C, int M, int N, int K) {
  __shared__ __align__(16) bf16 lA[128 * 32];
  __shared__ __align__(16) bf16 lB[128 * 32];
  const int tid = threadIdx.x;
  const int lane = tid & 63, wave = tid >> 6;
  const int quad = lane >> 4, l16 = lane & 15;
  const int tileM = blockIdx.y * 128, tileN = blockIdx.x * 128;
  const int wm = (wave >> 1) * 64, wn = (wave & 1) * 64;

  f32x4 acc[4][4] = {};

  for (int kt = 0; kt < K; kt += 32) {
    __syncthreads();
    {
      int g0 = tid, g1 = tid + 256;
      gload_lds16(A + (size_t)(tileM + (g0 >> 2)) * K + kt + (g0 & 3) * 8,
                  (char*)lA + wave * 1024);
      gload_lds16(A + (size_t)(tileM + (g1 >> 2)) * K + kt + (g1 & 3) * 8,
                  (char*)lA + 4096 + wave * 1024);
      gload_lds16(BT + (size_t)(tileN + (g0 >> 2)) * K + kt + (g0 & 3) * 8,
                  (char*)lB + wave * 1024);
      gload_lds16(BT + (size_t)(tileN + (g1 >> 2)) * K + kt + (g1 & 3) * 8,
                  (char*)lB + 4096 + wave * 1024);
    }
    __syncthreads();

    bf16x8 af[4], bfr[4];
#pragma unroll
    for (int i = 0; i < 4; ++i)
      af[i] = *(const bf16x8*)&lA[(wm + i * 16 + l16) * 32 + quad * 8];
#pragma unroll
    for (int j = 0; j < 4; ++j)
      bfr[j] = *(const bf16x8*)&lB[(wn + j * 16 + l16) * 32 + quad * 8];
#pragma unroll
    for (int i = 0; i < 4; ++i)
#pragma unroll
      for (int j = 0; j < 4; ++j)
        acc[i][j] = __builtin_amdgcn_mfma_f32_16x16x32_bf16(af[i], bfr[j], acc[i][j], 0, 0, 0);
  }

#pragma unroll
  for (int i = 0; i < 4; ++i)
#pragma unroll
    for (int j = 0; j < 4; ++j)
#pragma unroll
      for (int r = 0; r < 4; ++r) {
        int row = tileM + wm + i * 16 + quad * 4 + r;
        int col = tileN + wn + j * 16 + l16;
        C[(size_t)row * N + col] = (OutT)acc[i][j][r];
      }
}

// ---------------- fused RMSNorm + RoPE + scatter ----------------
// qkv [8192][3072] bf16 -> q [B][NH][S][HD], k/v [B][NKV][S][HD]
__global__ __launch_bounds__(256) void rmsnorm_rope(
    const bf16* __restrict__ qkv, const float* __restrict__ cosT,
    const float* __restrict__ sinT, bf16* __restrict__ qb,
    bf16* __restrict__ kb, bf16* __restrict__ vb) {
  int wave = threadIdx.x >> 6, lane = threadIdx.x & 63;
  int task = blockIdx.x * 4 + wave;          // row*24 + chunk
  int row = task / 24, chunk = task % 24;
  int b = row >> 11, s = row & 2047;

  const bf16* src = qkv + (size_t)row * QKVN + chunk * 128 + lane * 2;
  bf16x2 v = *(const bf16x2*)src;
  bf16 o0, o1;
  if (chunk >= 20) {  // V: passthrough
    o0 = v[0]; o1 = v[1];
  } else {            // Q/K: RMSNorm + RoPE
    float x0 = (float)v[0], x1 = (float)v[1];
    float ss = x0 * x0 + x1 * x1;
#pragma unroll
    for (int off = 1; off < 64; off <<= 1) ss += __shfl_xor(ss, off);
    float rms = rsqrtf(ss * (1.0f / 128.0f) + 1.1920929e-07f);
    x0 *= rms; x1 *= rms;
    float p0 = __shfl_xor(x0, 32), p1 = __shfl_xor(x1, 32);
    int j0 = (lane & 31) * 2;
    float c0 = cosT[s * 64 + j0], c1 = cosT[s * 64 + j0 + 1];
    float s0 = sinT[s * 64 + j0], s1 = sinT[s * 64 + j0 + 1];
    float r0, r1;
    if (lane < 32) { r0 = x0 * c0 + p0 * s0; r1 = x1 * c1 + p1 * s1; }
    else           { r0 = x0 * c0 - p0 * s0; r1 = x1 * c1 - p1 * s1; }
    o0 = (bf16)r0; o1 = (bf16)r1;
  }
  bf16* dst;
  int d = lane * 2;
  if (chunk < 16)      dst = qb + ((size_t)(b * NH + chunk) * SEQ + s) * HD + d;
  else if (chunk < 20) dst = kb + ((size_t)(b * NKV + (chunk - 16)) * SEQ + s) * HD + d;
  else                 dst = vb + ((size_t)(b * NKV + (chunk - 20)) * SEQ + s) * HD + d;
  bf16x2 t = {o0, o1};
  *(bf16x2*)dst = t;
}

// ---------------- flash attention ----------------
// q [B][NH][S][HD], k [B][NKV][S][HD], vT [B][NKV][HD][S] -> y [B*S][DIM]
__global__ __launch_bounds__(256, 2) void attn_kernel(
    const bf16* __restrict__ qb, const bf16* __restrict__ kb,
    const bf16* __restrict__ vTb, bf16* __restrict__ y) {
  __shared__ __align__(16) char sm[65536];
  bf16* lKP = (bf16*)sm;            // K tile [128][128]; later P tile (col-swizzled)
  bf16* lV  = (bf16*)(sm + 32768);  // V^T tile [128 d][128 kv]

  const int tid = threadIdx.x;
  const int lane = tid & 63, wave = tid >> 6;
  const int quad = lane >> 4, l16 = lane & 15;
  const int qt = (int)gridDim.x - 1 - (int)blockIdx.x;  // heavy q-tiles first
  const int h = blockIdx.y, b = blockIdx.z;
  const int kvh = h >> 2;
  const int q0 = qt * 128;
  const int wm = wave * 32;

  const bf16* qh = qb + (size_t)(b * NH + h) * SEQ * HD;
  const bf16* kh = kb + (size_t)(b * NKV + kvh) * SEQ * HD;
  const bf16* vh = vTb + (size_t)(b * NKV + kvh) * HD * SEQ;

  // Q fragments in registers: A[m=q][k=d], 2 m-blocks x 4 k-steps
  bf16x8 qf[2][4];
#pragma unroll
  for (int i = 0; i < 2; ++i) {
    int s = q0 + wm + i * 16 + l16;
#pragma unroll
    for (int ks = 0; ks < 4; ++ks)
      qf[i][ks] = *(const bf16x8*)&qh[(size_t)s * HD + ks * 32 + quad * 8];
  }

  f32x4 oacc[2][8] = {};
  float mrow[2][4], lrow[2][4];
#pragma unroll
  for (int i = 0; i < 2; ++i)
#pragma unroll
    for (int r = 0; r < 4; ++r) { mrow[i][r] = -1e30f; lrow[i][r] = 0.f; }

  const float scale = 0.08838834764831845f;  // 128^-0.5

  for (int kv0 = 0; kv0 <= q0; kv0 += 128) {
    __syncthreads();  // prior iteration's K/P/V reads complete
    // stage K and V^T tiles; XOR-swizzle 8-el column groups by (row>>2)&3
#pragma unroll
    for (int inst = 0; inst < 8; ++inst) {
      int g = inst * 256 + tid;
      int R = g >> 4;
      int Cg = (g & 15) ^ (((R >> 2) & 3) << 1);
      gload_lds16(kh + (size_t)(kv0 + R) * HD + Cg * 8, (char*)lKP + inst * 4096 + wave * 1024);
      gload_lds16(vh + (size_t)R * SEQ + kv0 + Cg * 8, (char*)lV + inst * 4096 + wave * 1024);
    }
    __syncthreads();

    // S = Q K^T  (per wave: 32 q-rows x 128 kv)
    f32x4 sacc[2][8] = {};
#pragma unroll
    for (int ks = 0; ks < 4; ++ks) {
      int colK = (ks * 32 + quad * 8) ^ ((l16 >> 2) << 4);
      bf16x8 bfr[8];
#pragma unroll
      for (int nb = 0; nb < 8; ++nb)
        bfr[nb] = *(const bf16x8*)&lKP[(nb * 16 + l16) * 128 + colK];
#pragma unroll
      for (int i = 0; i < 2; ++i)
#pragma unroll
        for (int nb = 0; nb < 8; ++nb)
          sacc[i][nb] = __builtin_amdgcn_mfma_f32_16x16x32_bf16(qf[i][ks], bfr[nb], sacc[i][nb], 0, 0, 0);
    }

    // online softmax; row stats live in the 16-lane quad (no LDS)
    const bool diag = (kv0 == q0);
    float alpha[2][4];
#pragma unroll
    for (int i = 0; i < 2; ++i)
#pragma unroll
      for (int r = 0; r < 4; ++r) {
        float mx = -1e30f;
#pragma unroll
        for (int nb = 0; nb < 8; ++nb) {
          float v = sacc[i][nb][r] * scale;
          if (diag && (nb * 16 + l16) > (wm + i * 16 + quad * 4 + r)) v = -1e30f;
          sacc[i][nb][r] = v;
          mx = fmaxf(mx, v);
        }
        mx = fmaxf(mx, __shfl_xor(mx, 1));
        mx = fmaxf(mx, __shfl_xor(mx, 2));
        mx = fmaxf(mx, __shfl_xor(mx, 4));
        mx = fmaxf(mx, __shfl_xor(mx, 8));
        float mn = fmaxf(mrow[i][r], mx);
        float al = __expf(mrow[i][r] - mn);
        mrow[i][r] = mn;
        alpha[i][r] = al;
        float sum = 0.f;
#pragma unroll
        for (int nb = 0; nb < 8; ++nb) {
          float p = __expf(sacc[i][nb][r] - mn);
          sacc[i][nb][r] = p;
          sum += p;
        }
        sum += __shfl_xor(sum, 1);
        sum += __shfl_xor(sum, 2);
        sum += __shfl_xor(sum, 4);
        sum += __shfl_xor(sum, 8);
        lrow[i][r] = lrow[i][r] * al + sum;
      }

#pragma unroll
    for (int i = 0; i < 2; ++i)
#pragma unroll
      for (int nd = 0; nd < 8; ++nd)
#pragma unroll
        for (int r = 0; r < 4; ++r)
          oacc[i][nd][r] *= alpha[i][r];

    __syncthreads();  // all waves done reading K before P overwrites it
    // P -> LDS (aliases K region), col XOR-swizzled by quad == (row>>2)&3
#pragma unroll
    for (int i = 0; i < 2; ++i)
#pragma unroll
      for (int nb = 0; nb < 8; ++nb)
#pragma unroll
        for (int r = 0; r < 4; ++r) {
          int row = wm + i * 16 + quad * 4 + r;
          int col = (nb * 16 + l16) ^ (quad << 4);
          lKP[row * 128 + col] = (bf16)sacc[i][nb][r];
        }

    // O += P V   (same-wave LDS write->read: no barrier needed)
#pragma unroll
    for (int ks = 0; ks < 4; ++ks) {
      int colP = (ks * 32 + quad * 8) ^ ((l16 >> 2) << 4);
      bf16x8 pf[2], vf[8];
#pragma unroll
      for (int i = 0; i < 2; ++i)
        pf[i] = *(const bf16x8*)&lKP[(wm + i * 16 + l16) * 128 + colP];
#pragma unroll
      for (int nd = 0; nd < 8; ++nd)
        vf[nd] = *(const bf16x8*)&lV[(nd * 16 + l16) * 128 + colP];
#pragma unroll
      for (int i = 0; i < 2; ++i)
#pragma unroll
        for (int nd = 0; nd < 8; ++nd)
          oacc[i][nd] = __builtin_amdgcn_mfma_f32_16x16x32_bf16(pf[i], vf[nd], oacc[i][nd], 0, 0, 0);
    }
  }

  // epilogue: O/l -> y[B*S][DIM] (col = h*HD + d)
#pragma unroll
  for (int i = 0; i < 2; ++i)
#pragma unroll
    for (int r = 0; r < 4; ++r) {
      float inv = 1.0f / lrow[i][r];
      int srow = q0 + wm + i * 16 + quad * 4 + r;
      size_t base = ((size_t)(b * SEQ + srow)) * DIM + h * HD;
#pragma unroll
      for (int nd = 0; nd < 8; ++nd)
        y[base + nd * 16 + l16] = (bf16)(oacc[i][nd][r] * inv);
    }
}

// ---------------- launcher ----------------

extern "C" void kernel_launch(void* const* d_in, const int* in_sizes, int n_in,
                              void* d_out, int out_size, void* d_ws, size_t ws_size,
                              hipStream_t stream) {
  const float* x    = (const float*)d_in[0];
  const float* Wqkv = (const float*)d_in[1];
  const float* Wout = (const float*)d_in[2];
  float* out = (float*)d_out;

  char* w = (char*)d_ws;
  auto carve = [&](size_t bytes) -> char* {
    char* p = w;
    w += (bytes + 255) & ~(size_t)255;
    return p;
  };
  bf16* xb   = (bf16*)carve((size_t)ROWS * DIM * 2);        // 32 MB; later aliased by qbuf
  bf16* WqT  = (bf16*)carve((size_t)QKVN * DIM * 2);        // 12 MB; later aliased by vT
  bf16* WoT  = (bf16*)carve((size_t)DIM * DIM * 2);         // 8 MB
  bf16* qkv  = (bf16*)carve((size_t)ROWS * QKVN * 2);       // 48 MB; later aliased by ybuf
  bf16* kbuf = (bf16*)carve((size_t)BATCH * NKV * SEQ * HD * 2);
  bf16* vbuf = (bf16*)carve((size_t)BATCH * NKV * SEQ * HD * 2);
  float* cosT = (float*)carve((size_t)SEQ * 64 * 4);
  float* sinT = (float*)carve((size_t)SEQ * 64 * 4);

  bf16* qbuf = xb;    // xb dead after GEMM1
  bf16* vT   = WqT;   // WqT dead after GEMM1
  bf16* ybuf = qkv;   // qkv dead after rmsnorm_rope

  convert_f32_bf16<<<ROWS * DIM / 1024, 256, 0, stream>>>(x, xb, ROWS * DIM);
  transpose_w<<<dim3(QKVN / 64, DIM / 64), 256, 0, stream>>>(Wqkv, WqT, DIM, QKVN);
  transpose_w<<<dim3(DIM / 64, DIM / 64), 256, 0, stream>>>(Wout, WoT, DIM, DIM);
  rope_tables<<<SEQ * 64 / 256, 256, 0, stream>>>(cosT, sinT);

  gemm_bt<bf16><<<dim3(QKVN / 128, ROWS / 128), 256, 0, stream>>>(xb, WqT, qkv, ROWS, QKVN, DIM);
  rmsnorm_rope<<<ROWS * 24 / 4, 256, 0, stream>>>(qkv, cosT, sinT, qbuf, kbuf, vbuf);
  transpose_v<<<dim3(HD / 64, SEQ / 64, BATCH * NKV), 256, 0, stream>>>(vbuf, vT);
  attn_kernel<<<dim3(SEQ / 128, NH, BATCH), 256, 0, stream>>>(qbuf, kbuf, vT, ybuf);
  gemm_bt<float><<<dim3(DIM / 128, ROWS / 128), 256, 0, stream>>>(ybuf, WoT, out, ROWS, DIM, DIM);
}

// Round 2
// 649.374 us; speedup vs baseline: 1.6830x; 1.6830x over previous
//
#include <hip/hip_runtime.h>

#define DIM    2048
#define SEQ    2048
#define BATCH  4
#define NH     16
#define NKV    4
#define HD     128
#define QKVN   3072
#define ROWS   (BATCH*SEQ)   // 8192

typedef __bf16 bf16;
typedef __bf16 bf16x2 __attribute__((ext_vector_type(2)));
typedef __bf16 bf16x4 __attribute__((ext_vector_type(4)));
typedef __bf16 bf16x8 __attribute__((ext_vector_type(8)));
typedef float  f32x4  __attribute__((ext_vector_type(4)));

__device__ __forceinline__ void gload_lds16(const void* g, void* l) {
  __builtin_amdgcn_global_load_lds(
      (const __attribute__((address_space(1))) void*)g,
      (__attribute__((address_space(3))) void*)l, 16, 0, 0);
}

// ---------------- small prep kernels ----------------

__global__ void convert_f32_bf16(const float* __restrict__ in, bf16* __restrict__ out, int n) {
  int i = (blockIdx.x * 256 + threadIdx.x) * 4;
  if (i < n) {
    float4 v = *(const float4*)(in + i);
    bf16x4 t = {(bf16)v.x, (bf16)v.y, (bf16)v.z, (bf16)v.w};
    *(bf16x4*)(out + i) = t;
  }
}

// in [R][C] fp32 -> out [C][R] bf16
__global__ void transpose_w(const float* __restrict__ in, bf16* __restrict__ out, int R, int C) {
  __shared__ float t[64][65];
  int c0 = blockIdx.x * 64, r0 = blockIdx.y * 64;
  int tx = threadIdx.x & 63, ty = threadIdx.x >> 6;
  for (int i = ty; i < 64; i += 4) t[i][tx] = in[(size_t)(r0 + i) * C + c0 + tx];
  __syncthreads();
  for (int i = ty; i < 64; i += 4) out[(size_t)(c0 + i) * R + r0 + tx] = (bf16)t[tx][i];
}

// v [z][2048][128] bf16 -> vT [z][128][2048] bf16
__global__ void transpose_v(const bf16* __restrict__ vb, bf16* __restrict__ vT) {
  __shared__ bf16 t[64][65];
  int z = blockIdx.z;
  const bf16* in = vb + (size_t)z * SEQ * HD;
  bf16* out = vT + (size_t)z * HD * SEQ;
  int d0 = blockIdx.x * 64, s0 = blockIdx.y * 64;
  int tx = threadIdx.x & 63, ty = threadIdx.x >> 6;
  for (int i = ty; i < 64; i += 4) t[i][tx] = in[(size_t)(s0 + i) * HD + d0 + tx];
  __syncthreads();
  for (int i = ty; i < 64; i += 4) out[(size_t)(d0 + i) * SEQ + s0 + tx] = t[tx][i];
}

__global__ void rope_tables(float* __restrict__ cosT, float* __restrict__ sinT) {
  int idx = blockIdx.x * 256 + threadIdx.x;  // SEQ*64
  int s = idx >> 6, j = idx & 63;
  float inv = powf(10000.0f, -(float)j * (1.0f / 64.0f));
  float ang = (float)s * inv;
  cosT[idx] = cosf(ang);
  sinT[idx] = sinf(ang);
}

// ---------------- m97-style bf16 MFMA GEMM, B transposed ----------------
// C[M][N] = A[M][K] * BT[N][K]^T ; tiles 128x128, BK=32, 256 threads
template <typename OutT>
__global__ __launch_bounds__(256, 2) void gemm_bt(
    const bf16* __restrict__ A, const bf16* __restrict__ BT,
    OutT* __restrict__ C, int M, int N, int K) {
  __shared__ __align__(16) bf16 lA[128 * 32];
  __shared__ __align__(16) bf16 lB[128 * 32];
  const int tid = threadIdx.x;
  const int lane = tid & 63, wave = tid >> 6;
  const int quad = lane >> 4, l16 = lane & 15;
  const int tileM = blockIdx.y * 128, tileN = blockIdx.x * 128;
  const int wm = (wave >> 1) * 64, wn = (wave & 1) * 64;

  f32x4 acc[4][4] = {};

  for (int kt = 0; kt < K; kt += 32) {
    __syncthreads();
    {
      int g0 = tid, g1 = tid + 256;
      gload_lds16(A + (size_t)(tileM + (g0 >> 2)) * K + kt + (g0 & 3) * 8,
                  (char*)lA + wave * 1024);
      gload_lds16(A + (size_t)(tileM + (g1 >> 2)) * K + kt + (g1 & 3) * 8,
                  (char*)lA + 4096 + wave * 1024);
      gload_lds16(BT + (size_t)(tileN + (g0 >> 2)) * K + kt + (g0 & 3) * 8,
                  (char*)lB + wave * 1024);
      gload_lds16(BT + (size_t)(tileN + (g1 >> 2)) * K + kt + (g1 & 3) * 8,
                  (char*)lB + 4096 + wave * 1024);
    }
    __syncthreads();

    bf16x8 af[4], bfr[4];
#pragma unroll
    for (int i = 0; i < 4; ++i)
      af[i] = *(const bf16x8*)&lA[(wm + i * 16 + l16) * 32 + quad * 8];
#pragma unroll
    for (int j = 0; j < 4; ++j)
      bfr[j] = *(const bf16x8*)&lB[(wn + j * 16 + l16) * 32 + quad * 8];
#pragma unroll
    for (int i = 0; i < 4; ++i)
#pragma unroll
      for (int j = 0; j < 4; ++j)
        acc[i][j] = __builtin_amdgcn_mfma_f32_16x16x32_bf16(af[i], bfr[j], acc[i][j], 0, 0, 0);
  }

#pragma unroll
  for (int i = 0; i < 4; ++i)
#pragma unroll
    for (int j = 0; j < 4; ++j)
#pragma unroll
      for (int r = 0; r < 4; ++r) {
        int row = tileM + wm + i * 16 + quad * 4 + r;
        int col = tileN + wn + j * 16 + l16;
        C[(size_t)row * N + col] = (OutT)acc[i][j][r];
      }
}

// ---------------- fused RMSNorm + RoPE + scatter ----------------
// qkv [8192][3072] bf16 -> q [B][NH][S][HD], k/v [B][NKV][S][HD]
__global__ __launch_bounds__(256) void rmsnorm_rope(
    const bf16* __restrict__ qkv, const float* __restrict__ cosT,
    const float* __restrict__ sinT, bf16* __restrict__ qb,
    bf16* __restrict__ kb, bf16* __restrict__ vb) {
  int wave = threadIdx.x >> 6, lane = threadIdx.x & 63;
  int task = blockIdx.x * 4 + wave;          // row*24 + chunk
  int row = task / 24, chunk = task % 24;
  int b = row >> 11, s = row & 2047;

  const bf16* src = qkv + (size_t)row * QKVN + chunk * 128 + lane * 2;
  bf16x2 v = *(const bf16x2*)src;
  bf16 o0, o1;
  if (chunk >= 20) {  // V: passthrough
    o0 = v[0]; o1 = v[1];
  } else {            // Q/K: RMSNorm + RoPE
    float x0 = (float)v[0], x1 = (float)v[1];
    float ss = x0 * x0 + x1 * x1;
#pragma unroll
    for (int off = 1; off < 64; off <<= 1) ss += __shfl_xor(ss, off);
    float rms = rsqrtf(ss * (1.0f / 128.0f) + 1.1920929e-07f);
    x0 *= rms; x1 *= rms;
    float p0 = __shfl_xor(x0, 32), p1 = __shfl_xor(x1, 32);
    int j0 = (lane & 31) * 2;
    float c0 = cosT[s * 64 + j0], c1 = cosT[s * 64 + j0 + 1];
    float s0 = sinT[s * 64 + j0], s1 = sinT[s * 64 + j0 + 1];
    float r0, r1;
    if (lane < 32) { r0 = x0 * c0 + p0 * s0; r1 = x1 * c1 + p1 * s1; }
    else           { r0 = x0 * c0 - p0 * s0; r1 = x1 * c1 - p1 * s1; }
    o0 = (bf16)r0; o1 = (bf16)r1;
  }
  bf16* dst;
  int d = lane * 2;
  if (chunk < 16)      dst = qb + ((size_t)(b * NH + chunk) * SEQ + s) * HD + d;
  else if (chunk < 20) dst = kb + ((size_t)(b * NKV + (chunk - 16)) * SEQ + s) * HD + d;
  else                 dst = vb + ((size_t)(b * NKV + (chunk - 20)) * SEQ + s) * HD + d;
  bf16x2 t = {o0, o1};
  *(bf16x2*)dst = t;
}

// ---------------- flash attention ----------------
// Per block: 64 q-rows (wave owns 16), kv tile 128. LDS 64KB (K|P + V).
// Swizzle: 16B group g of row r stored at g^(r&15)  -> conflict-free b128 reads.
// q [B][NH][S][HD], k [B][NKV][S][HD], vT [B][NKV][HD][S] -> y [B*S][DIM]
__global__ __launch_bounds__(256, 2) void attn_kernel(
    const bf16* __restrict__ qb, const bf16* __restrict__ kb,
    const bf16* __restrict__ vTb, bf16* __restrict__ y) {
  __shared__ __align__(16) char sm[65536];
  bf16* lKP = (bf16*)sm;            // K tile [128 kv][128 d]; P tile [64 q][128 kv] aliases
  bf16* lV  = (bf16*)(sm + 32768);  // V^T tile [128 d][128 kv]

  const int tid = threadIdx.x;
  const int lane = tid & 63, wave = tid >> 6;
  const int quad = lane >> 4, l16 = lane & 15;
  const int qt = (int)gridDim.x - 1 - (int)blockIdx.x;  // heavy q-tiles first
  const int h = blockIdx.y, b = blockIdx.z;
  const int kvh = h >> 2;
  const int q0 = qt * 64;
  const int wm = wave * 16;         // wave's q-rows within tile

  const bf16* qh = qb + (size_t)(b * NH + h) * SEQ * HD;
  const bf16* kh = kb + (size_t)(b * NKV + kvh) * SEQ * HD;
  const bf16* vh = vTb + (size_t)(b * NKV + kvh) * HD * SEQ;

  // Q fragments: A[m=l16][k=d], 4 k-steps (HD=128)
  bf16x8 qf[4];
#pragma unroll
  for (int ks = 0; ks < 4; ++ks)
    qf[ks] = *(const bf16x8*)&qh[(size_t)(q0 + wm + l16) * HD + ks * 32 + quad * 8];

  f32x4 oacc[8] = {};
  float mrow[4], lrow[4];
#pragma unroll
  for (int r = 0; r < 4; ++r) { mrow[r] = -1e30f; lrow[r] = 0.f; }

  const float scale = 0.08838834764831845f;  // 128^-0.5

  for (int kv0 = 0; kv0 <= q0; kv0 += 128) {
    __syncthreads();  // staged data for this iter complete; prior P/V reads done
    // stage K [128][128] and V^T [128][128]; group swizzled by row&15
#pragma unroll
    for (int inst = 0; inst < 8; ++inst) {
      int slot = inst * 256 + tid;
      int R = slot >> 4;
      int gg = (slot & 15) ^ (R & 15);
      gload_lds16(kh + (size_t)(kv0 + R) * HD + gg * 8, (char*)lKP + inst * 4096 + wave * 1024);
      gload_lds16(vh + (size_t)R * SEQ + kv0 + gg * 8, (char*)lV + inst * 4096 + wave * 1024);
    }
    __syncthreads();

    // S = Q K^T  (wave: 16 q-rows x 128 kv)
    f32x4 sacc[8] = {};
#pragma unroll
    for (int ks = 0; ks < 4; ++ks) {
      int bg = ks * 4 + quad;
      bf16x8 bfr[8];
#pragma unroll
      for (int nb = 0; nb < 8; ++nb)
        bfr[nb] = *(const bf16x8*)&lKP[(nb * 16 + l16) * 128 + (bg ^ l16) * 8];
#pragma unroll
      for (int nb = 0; nb < 8; ++nb)
        sacc[nb] = __builtin_amdgcn_mfma_f32_16x16x32_bf16(qf[ks], bfr[nb], sacc[nb], 0, 0, 0);
    }

    // online softmax; row stats live in the 16-lane quad (no LDS)
    const bool diag = (kv0 + 128 > q0);
    float alpha[4];
#pragma unroll
    for (int r = 0; r < 4; ++r) {
      int qrow = q0 + wm + quad * 4 + r;
      float mx = -1e30f;
#pragma unroll
      for (int nb = 0; nb < 8; ++nb) {
        float v = sacc[nb][r] * scale;
        if (diag && (kv0 + nb * 16 + l16) > qrow) v = -1e30f;
        sacc[nb][r] = v;
        mx = fmaxf(mx, v);
      }
      mx = fmaxf(mx, __shfl_xor(mx, 1));
      mx = fmaxf(mx, __shfl_xor(mx, 2));
      mx = fmaxf(mx, __shfl_xor(mx, 4));
      mx = fmaxf(mx, __shfl_xor(mx, 8));
      float mn = fmaxf(mrow[r], mx);
      float al = __expf(mrow[r] - mn);
      mrow[r] = mn;
      alpha[r] = al;
      float sum = 0.f;
#pragma unroll
      for (int nb = 0; nb < 8; ++nb) {
        float p = __expf(sacc[nb][r] - mn);
        sacc[nb][r] = p;
        sum += p;
      }
      sum += __shfl_xor(sum, 1);
      sum += __shfl_xor(sum, 2);
      sum += __shfl_xor(sum, 4);
      sum += __shfl_xor(sum, 8);
      lrow[r] = lrow[r] * al + sum;
    }

#pragma unroll
    for (int nd = 0; nd < 8; ++nd)
#pragma unroll
      for (int r = 0; r < 4; ++r)
        oacc[nd][r] *= alpha[r];

    __syncthreads();  // all waves done reading K before P overwrites it
    // P [64 q][128 kv] -> LDS (aliases K region), group ^= row&15
#pragma unroll
    for (int nb = 0; nb < 8; ++nb)
#pragma unroll
      for (int r = 0; r < 4; ++r) {
        int row = wm + quad * 4 + r;
        int col = nb * 16 + l16;
        int scol = (((col >> 3) ^ (row & 15)) << 3) | (col & 7);
        lKP[row * 128 + scol] = (bf16)sacc[nb][r];
      }

    // O += P V   (pf reads only own wave's rows: no barrier needed)
#pragma unroll
    for (int ks = 0; ks < 4; ++ks) {
      int bg = ks * 4 + quad;
      bf16x8 pf = *(const bf16x8*)&lKP[(wm + l16) * 128 + (bg ^ l16) * 8];
      bf16x8 vf[8];
#pragma unroll
      for (int nd = 0; nd < 8; ++nd)
        vf[nd] = *(const bf16x8*)&lV[(nd * 16 + l16) * 128 + (bg ^ l16) * 8];
#pragma unroll
      for (int nd = 0; nd < 8; ++nd)
        oacc[nd] = __builtin_amdgcn_mfma_f32_16x16x32_bf16(pf, vf[nd], oacc[nd], 0, 0, 0);
    }
  }

  // epilogue: O/l -> y[B*S][DIM] (col = h*HD + d)
#pragma unroll
  for (int r = 0; r < 4; ++r) {
    float inv = 1.0f / lrow[r];
    int srow = q0 + wm + quad * 4 + r;
    size_t base = ((size_t)(b * SEQ + srow)) * DIM + h * HD;
#pragma unroll
    for (int nd = 0; nd < 8; ++nd)
      y[base + nd * 16 + l16] = (bf16)(oacc[nd][r] * inv);
  }
}

// ---------------- launcher ----------------

extern "C" void kernel_launch(void* const* d_in, const int* in_sizes, int n_in,
                              void* d_out, int out_size, void* d_ws, size_t ws_size,
                              hipStream_t stream) {
  const float* x    = (const float*)d_in[0];
  const float* Wqkv = (const float*)d_in[1];
  const float* Wout = (const float*)d_in[2];
  float* out = (float*)d_out;

  char* w = (char*)d_ws;
  auto carve = [&](size_t bytes) -> char* {
    char* p = w;
    w += (bytes + 255) & ~(size_t)255;
    return p;
  };
  bf16* xb   = (bf16*)carve((size_t)ROWS * DIM * 2);        // 32 MB; later aliased by qbuf
  bf16* WqT  = (bf16*)carve((size_t)QKVN * DIM * 2);        // 12 MB; later aliased by vT
  bf16* WoT  = (bf16*)carve((size_t)DIM * DIM * 2);         // 8 MB
  bf16* qkv  = (bf16*)carve((size_t)ROWS * QKVN * 2);       // 48 MB; later aliased by ybuf
  bf16* kbuf = (bf16*)carve((size_t)BATCH * NKV * SEQ * HD * 2);
  bf16* vbuf = (bf16*)carve((size_t)BATCH * NKV * SEQ * HD * 2);
  float* cosT = (float*)carve((size_t)SEQ * 64 * 4);
  float* sinT = (float*)carve((size_t)SEQ * 64 * 4);

  bf16* qbuf = xb;    // xb dead after GEMM1
  bf16* vT   = WqT;   // WqT dead after GEMM1
  bf16* ybuf = qkv;   // qkv dead after rmsnorm_rope

  convert_f32_bf16<<<ROWS * DIM / 1024, 256, 0, stream>>>(x, xb, ROWS * DIM);
  transpose_w<<<dim3(QKVN / 64, DIM / 64), 256, 0, stream>>>(Wqkv, WqT, DIM, QKVN);
  transpose_w<<<dim3(DIM / 64, DIM / 64), 256, 0, stream>>>(Wout, WoT, DIM, DIM);
  rope_tables<<<SEQ * 64 / 256, 256, 0, stream>>>(cosT, sinT);

  gemm_bt<bf16><<<dim3(QKVN / 128, ROWS / 128), 256, 0, stream>>>(xb, WqT, qkv, ROWS, QKVN, DIM);
  rmsnorm_rope<<<ROWS * 24 / 4, 256, 0, stream>>>(qkv, cosT, sinT, qbuf, kbuf, vbuf);
  transpose_v<<<dim3(HD / 64, SEQ / 64, BATCH * NKV), 256, 0, stream>>>(vbuf, vT);
  attn_kernel<<<dim3(SEQ / 64, NH, BATCH), 256, 0, stream>>>(qbuf, kbuf, vT, ybuf);
  gemm_bt<float><<<dim3(DIM / 128, ROWS / 128), 256, 0, stream>>>(ybuf, WoT, out, ROWS, DIM, DIM);
}

// Round 3
// 518.650 us; speedup vs baseline: 2.1072x; 1.2520x over previous
//
#include <hip/hip_runtime.h>

#define DIM    2048
#define SEQ    2048
#define BATCH  4
#define NH     16
#define NKV    4
#define HD     128
#define QKVN   3072
#define ROWS   (BATCH*SEQ)   // 8192

typedef __bf16 bf16;
typedef __bf16 bf16x2 __attribute__((ext_vector_type(2)));
typedef __bf16 bf16x4 __attribute__((ext_vector_type(4)));
typedef __bf16 bf16x8 __attribute__((ext_vector_type(8)));
typedef float  f32x4  __attribute__((ext_vector_type(4)));
typedef float  f32x16 __attribute__((ext_vector_type(16)));

typedef union { bf16x4 v; unsigned int u[2]; } b4u;
typedef union { bf16x8 v8; bf16x4 v4[2]; } b8u;

// scale(1/sqrt(128)) * log2(e) — folded into Q at rmsnorm time
#define SL2E 0.12752365234813963f

__device__ __forceinline__ void gload_lds16(const void* g, void* l) {
  __builtin_amdgcn_global_load_lds(
      (const __attribute__((address_space(1))) void*)g,
      (__attribute__((address_space(3))) void*)l, 16, 0, 0);
}

// ---------------- small prep kernels ----------------

__global__ void convert_f32_bf16(const float* __restrict__ in, bf16* __restrict__ out, int n) {
  int i = (blockIdx.x * 256 + threadIdx.x) * 4;
  if (i < n) {
    float4 v = *(const float4*)(in + i);
    bf16x4 t = {(bf16)v.x, (bf16)v.y, (bf16)v.z, (bf16)v.w};
    *(bf16x4*)(out + i) = t;
  }
}

// in [R][C] fp32 -> out [C][R] bf16
__global__ void transpose_w(const float* __restrict__ in, bf16* __restrict__ out, int R, int C) {
  __shared__ float t[64][65];
  int c0 = blockIdx.x * 64, r0 = blockIdx.y * 64;
  int tx = threadIdx.x & 63, ty = threadIdx.x >> 6;
  for (int i = ty; i < 64; i += 4) t[i][tx] = in[(size_t)(r0 + i) * C + c0 + tx];
  __syncthreads();
  for (int i = ty; i < 64; i += 4) out[(size_t)(c0 + i) * R + r0 + tx] = (bf16)t[tx][i];
}

// v [z][2048][128] bf16 -> vT [z][128][2048] bf16
__global__ void transpose_v(const bf16* __restrict__ vb, bf16* __restrict__ vT) {
  __shared__ bf16 t[64][65];
  int z = blockIdx.z;
  const bf16* in = vb + (size_t)z * SEQ * HD;
  bf16* out = vT + (size_t)z * HD * SEQ;
  int d0 = blockIdx.x * 64, s0 = blockIdx.y * 64;
  int tx = threadIdx.x & 63, ty = threadIdx.x >> 6;
  for (int i = ty; i < 64; i += 4) t[i][tx] = in[(size_t)(s0 + i) * HD + d0 + tx];
  __syncthreads();
  for (int i = ty; i < 64; i += 4) out[(size_t)(d0 + i) * SEQ + s0 + tx] = t[tx][i];
}

__global__ void rope_tables(float* __restrict__ cosT, float* __restrict__ sinT) {
  int idx = blockIdx.x * 256 + threadIdx.x;  // SEQ*64
  int s = idx >> 6, j = idx & 63;
  float inv = powf(10000.0f, -(float)j * (1.0f / 64.0f));
  float ang = (float)s * inv;
  cosT[idx] = cosf(ang);
  sinT[idx] = sinf(ang);
}

// ---------------- m97-style bf16 MFMA GEMM, B transposed ----------------
// C[M][N] = A[M][K] * BT[N][K]^T ; tiles 128x128, BK=32, 256 threads
template <typename OutT>
__global__ __launch_bounds__(256, 2) void gemm_bt(
    const bf16* __restrict__ A, const bf16* __restrict__ BT,
    OutT* __restrict__ C, int M, int N, int K) {
  __shared__ __align__(16) bf16 lA[128 * 32];
  __shared__ __align__(16) bf16 lB[128 * 32];
  const int tid = threadIdx.x;
  const int lane = tid & 63, wave = tid >> 6;
  const int quad = lane >> 4, l16 = lane & 15;
  const int tileM = blockIdx.y * 128, tileN = blockIdx.x * 128;
  const int wm = (wave >> 1) * 64, wn = (wave & 1) * 64;

  f32x4 acc[4][4] = {};

  for (int kt = 0; kt < K; kt += 32) {
    __syncthreads();
    {
      int g0 = tid, g1 = tid + 256;
      gload_lds16(A + (size_t)(tileM + (g0 >> 2)) * K + kt + (g0 & 3) * 8,
                  (char*)lA + wave * 1024);
      gload_lds16(A + (size_t)(tileM + (g1 >> 2)) * K + kt + (g1 & 3) * 8,
                  (char*)lA + 4096 + wave * 1024);
      gload_lds16(BT + (size_t)(tileN + (g0 >> 2)) * K + kt + (g0 & 3) * 8,
                  (char*)lB + wave * 1024);
      gload_lds16(BT + (size_t)(tileN + (g1 >> 2)) * K + kt + (g1 & 3) * 8,
                  (char*)lB + 4096 + wave * 1024);
    }
    __syncthreads();

    bf16x8 af[4], bfr[4];
#pragma unroll
    for (int i = 0; i < 4; ++i)
      af[i] = *(const bf16x8*)&lA[(wm + i * 16 + l16) * 32 + quad * 8];
#pragma unroll
    for (int j = 0; j < 4; ++j)
      bfr[j] = *(const bf16x8*)&lB[(wn + j * 16 + l16) * 32 + quad * 8];
#pragma unroll
    for (int i = 0; i < 4; ++i)
#pragma unroll
      for (int j = 0; j < 4; ++j)
        acc[i][j] = __builtin_amdgcn_mfma_f32_16x16x32_bf16(af[i], bfr[j], acc[i][j], 0, 0, 0);
  }

#pragma unroll
  for (int i = 0; i < 4; ++i)
#pragma unroll
    for (int j = 0; j < 4; ++j)
#pragma unroll
      for (int r = 0; r < 4; ++r) {
        int row = tileM + wm + i * 16 + quad * 4 + r;
        int col = tileN + wn + j * 16 + l16;
        C[(size_t)row * N + col] = (OutT)acc[i][j][r];
      }
}

// ---------------- fused RMSNorm + RoPE + scatter ----------------
// qkv [8192][3072] bf16 -> q [B][NH][S][HD] (Q pre-scaled by SL2E), k/v [B][NKV][S][HD]
__global__ __launch_bounds__(256) void rmsnorm_rope(
    const bf16* __restrict__ qkv, const float* __restrict__ cosT,
    const float* __restrict__ sinT, bf16* __restrict__ qb,
    bf16* __restrict__ kb, bf16* __restrict__ vb) {
  int wave = threadIdx.x >> 6, lane = threadIdx.x & 63;
  int task = blockIdx.x * 4 + wave;          // row*24 + chunk
  int row = task / 24, chunk = task % 24;
  int b = row >> 11, s = row & 2047;

  const bf16* src = qkv + (size_t)row * QKVN + chunk * 128 + lane * 2;
  bf16x2 v = *(const bf16x2*)src;
  bf16 o0, o1;
  if (chunk >= 20) {  // V: passthrough
    o0 = v[0]; o1 = v[1];
  } else {            // Q/K: RMSNorm + RoPE
    float x0 = (float)v[0], x1 = (float)v[1];
    float ss = x0 * x0 + x1 * x1;
#pragma unroll
    for (int off = 1; off < 64; off <<= 1) ss += __shfl_xor(ss, off);
    float rms = rsqrtf(ss * (1.0f / 128.0f) + 1.1920929e-07f);
    x0 *= rms; x1 *= rms;
    float p0 = __shfl_xor(x0, 32), p1 = __shfl_xor(x1, 32);
    int j0 = (lane & 31) * 2;
    float c0 = cosT[s * 64 + j0], c1 = cosT[s * 64 + j0 + 1];
    float s0 = sinT[s * 64 + j0], s1 = sinT[s * 64 + j0 + 1];
    float r0, r1;
    if (lane < 32) { r0 = x0 * c0 + p0 * s0; r1 = x1 * c1 + p1 * s1; }
    else           { r0 = x0 * c0 - p0 * s0; r1 = x1 * c1 - p1 * s1; }
    if (chunk < 16) { r0 *= SL2E; r1 *= SL2E; }  // fold softmax scale*log2e into Q
    o0 = (bf16)r0; o1 = (bf16)r1;
  }
  bf16* dst;
  int d = lane * 2;
  if (chunk < 16)      dst = qb + ((size_t)(b * NH + chunk) * SEQ + s) * HD + d;
  else if (chunk < 20) dst = kb + ((size_t)(b * NKV + (chunk - 16)) * SEQ + s) * HD + d;
  else                 dst = vb + ((size_t)(b * NKV + (chunk - 20)) * SEQ + s) * HD + d;
  bf16x2 t = {o0, o1};
  *(bf16x2*)dst = t;
}

// ---------------- flash attention v3 ----------------
// 32x32x16 MFMA, S^T orientation (q on lanes), no-max softmax (Q pre-scaled),
// P stays in registers (half-wave shfl exchange), paired q-tiles for perfect
// static balance: 512 blocks == 2/CU, one resident pass, 17 kv-iters each.
// q [B][NH][S][HD], k [B][NKV][S][HD], vT [B][NKV][HD][S] -> y [B*S][DIM]
__global__ __launch_bounds__(256, 2) void attn_kernel(
    const bf16* __restrict__ qb, const bf16* __restrict__ kb,
    const bf16* __restrict__ vTb, bf16* __restrict__ y) {
  __shared__ __align__(16) char sm[65536];
  bf16* lK = (bf16*)sm;            // K tile [128 kv][128 d], 16B-group g stored at g^(row&15)
  bf16* lV = (bf16*)(sm + 32768);  // V^T tile [128 d][128 kv], same swizzle

  const int tid = threadIdx.x;
  const int lane = tid & 63, wave = tid >> 6;
  const int l32 = lane & 31, h = lane >> 5;
  const int pairI = blockIdx.x, hh = blockIdx.y, b = blockIdx.z;
  const int kvh = hh >> 2;

  const bf16* qh = qb + (size_t)(b * NH + hh) * SEQ * HD;
  const bf16* kh = kb + (size_t)(b * NKV + kvh) * SEQ * HD;
  const bf16* vh = vTb + (size_t)(b * NKV + kvh) * HD * SEQ;

  for (int t = 0; t < 2; ++t) {
    const int qt = t ? pairI : (15 - pairI);  // pair (p, 15-p): 17 iters total
    const int qtile = qt * 128;
    const int qrow = qtile + wave * 32 + l32;  // this lane's q row

    // Q fragments (B-operand): [n=q on l32][k = ks*16 + h*8 + j]
    bf16x8 qf[8];
#pragma unroll
    for (int ks = 0; ks < 8; ++ks)
      qf[ks] = *(const bf16x8*)&qh[(size_t)qrow * HD + ks * 16 + h * 8];

    f32x16 oacc[4] = {};
    float psum = 0.f;

    for (int kv0 = 0; kv0 <= qtile; kv0 += 128) {
      __syncthreads();
#pragma unroll
      for (int inst = 0; inst < 8; ++inst) {
        int slot = inst * 256 + tid;
        int R = slot >> 4;
        int gg = (slot & 15) ^ (R & 15);
        gload_lds16(kh + (size_t)(kv0 + R) * HD + gg * 8, (char*)lK + inst * 4096 + wave * 1024);
        gload_lds16(vh + (size_t)R * SEQ + kv0 + gg * 8, (char*)lV + inst * 4096 + wave * 1024);
      }
      __syncthreads();

      const bool diag = (kv0 == qtile);
      const int kvbMax = diag ? (wave + 1) : 4;  // skip fully-masked 32-kv blocks
      for (int kvb = 0; kvb < kvbMax; ++kvb) {
        // S^T = K Q^T : A = K (m=kv on l32), B = Q (n=q on l32)
        f32x16 sacc = {};
#pragma unroll
        for (int ks = 0; ks < 8; ++ks) {
          int row = kvb * 32 + l32;
          const bf16x8 af = *(const bf16x8*)&lK[row * 128 + (((ks * 2 + h) ^ (row & 15)) << 3)];
          sacc = __builtin_amdgcn_mfma_f32_32x32x16_bf16(af, qf[ks], sacc, 0, 0, 0);
        }
        // no-max softmax: p = exp2(sacc) (Q carries scale*log2e)
        float p[16];
        const bool msk = diag && (kvb == wave);
#pragma unroll
        for (int r = 0; r < 16; ++r) {
          float v = sacc[r];
          if (msk) {
            int kv = kv0 + kvb * 32 + (r & 3) + 4 * h + 8 * (r >> 2);
            if (kv > qrow) v = -1e30f;
          }
          float e = exp2f(v);
          p[r] = e;
          psum += e;
        }
        // pack 4-reg blocks to bf16x4 (C row blocks: kv = (r&3) + 4h + 8*(r>>2))
        b4u pk[4];
#pragma unroll
        for (int B = 0; B < 4; ++B) {
          bf16x4 t4 = {(bf16)p[4 * B], (bf16)p[4 * B + 1], (bf16)p[4 * B + 2], (bf16)p[4 * B + 3]};
          pk[B].v = t4;
        }
        // build PV A-frags (m=q on l32, k = 8h+j) via half-wave exchange; P never hits LDS
#pragma unroll
        for (int ss = 0; ss < 2; ++ss) {
          b4u own = pk[2 * ss + h];
          b4u send = pk[2 * ss + (h ^ 1)];
          b4u got;
          got.u[0] = __shfl_xor(send.u[0], 32);
          got.u[1] = __shfl_xor(send.u[1], 32);
          b8u fr;
          fr.v4[0] = h ? got.v : own.v;
          fr.v4[1] = h ? own.v : got.v;
          int ks2 = kvb * 2 + ss;
#pragma unroll
          for (int nd = 0; nd < 4; ++nd) {
            int row = nd * 32 + l32;
            const bf16x8 vf = *(const bf16x8*)&lV[row * 128 + (((ks2 * 2 + h) ^ (row & 15)) << 3)];
            oacc[nd] = __builtin_amdgcn_mfma_f32_32x32x16_bf16(fr.v8, vf, oacc[nd], 0, 0, 0);
          }
        }
      }
    }

    // epilogue: lane holds O cols d=nd*32+l32, rows q_local=(r&3)+4h+8*(r>>2)
    float lsum = psum + __shfl_xor(psum, 32);
#pragma unroll
    for (int r = 0; r < 16; ++r) {
      int ql = (r & 3) + 4 * h + 8 * (r >> 2);
      float li = 1.0f / __shfl(lsum, ql);
      size_t base = ((size_t)(b * SEQ + qtile + wave * 32 + ql)) * DIM + hh * HD;
#pragma unroll
      for (int nd = 0; nd < 4; ++nd)
        y[base + nd * 32 + l32] = (bf16)(oacc[nd][r] * li);
    }
  }
}

// ---------------- launcher ----------------

extern "C" void kernel_launch(void* const* d_in, const int* in_sizes, int n_in,
                              void* d_out, int out_size, void* d_ws, size_t ws_size,
                              hipStream_t stream) {
  const float* x    = (const float*)d_in[0];
  const float* Wqkv = (const float*)d_in[1];
  const float* Wout = (const float*)d_in[2];
  float* out = (float*)d_out;

  char* w = (char*)d_ws;
  auto carve = [&](size_t bytes) -> char* {
    char* p = w;
    w += (bytes + 255) & ~(size_t)255;
    return p;
  };
  bf16* xb   = (bf16*)carve((size_t)ROWS * DIM * 2);        // 32 MB; later aliased by qbuf
  bf16* WqT  = (bf16*)carve((size_t)QKVN * DIM * 2);        // 12 MB; later aliased by vT
  bf16* WoT  = (bf16*)carve((size_t)DIM * DIM * 2);         // 8 MB
  bf16* qkv  = (bf16*)carve((size_t)ROWS * QKVN * 2);       // 48 MB; later aliased by ybuf
  bf16* kbuf = (bf16*)carve((size_t)BATCH * NKV * SEQ * HD * 2);
  bf16* vbuf = (bf16*)carve((size_t)BATCH * NKV * SEQ * HD * 2);
  float* cosT = (float*)carve((size_t)SEQ * 64 * 4);
  float* sinT = (float*)carve((size_t)SEQ * 64 * 4);

  bf16* qbuf = xb;    // xb dead after GEMM1
  bf16* vT   = WqT;   // WqT dead after GEMM1
  bf16* ybuf = qkv;   // qkv dead after rmsnorm_rope

  convert_f32_bf16<<<ROWS * DIM / 1024, 256, 0, stream>>>(x, xb, ROWS * DIM);
  transpose_w<<<dim3(QKVN / 64, DIM / 64), 256, 0, stream>>>(Wqkv, WqT, DIM, QKVN);
  transpose_w<<<dim3(DIM / 64, DIM / 64), 256, 0, stream>>>(Wout, WoT, DIM, DIM);
  rope_tables<<<SEQ * 64 / 256, 256, 0, stream>>>(cosT, sinT);

  gemm_bt<bf16><<<dim3(QKVN / 128, ROWS / 128), 256, 0, stream>>>(xb, WqT, qkv, ROWS, QKVN, DIM);
  rmsnorm_rope<<<ROWS * 24 / 4, 256, 0, stream>>>(qkv, cosT, sinT, qbuf, kbuf, vbuf);
  transpose_v<<<dim3(HD / 64, SEQ / 64, BATCH * NKV), 256, 0, stream>>>(vbuf, vT);
  attn_kernel<<<dim3(8, NH, BATCH), 256, 0, stream>>>(qbuf, kbuf, vT, ybuf);
  gemm_bt<float><<<dim3(DIM / 128, ROWS / 128), 256, 0, stream>>>(ybuf, WoT, out, ROWS, DIM, DIM);
}